// Round 11
// baseline (179.218 us; speedup 1.0000x reference)
//
#include <hip/hip_runtime.h>

// Involution (B=8, H=W=192, C=64, G=4, K=3, R=4) — round 14.
// R13 post-mortem: barrier removal NEUTRAL (~71us profiled, harness 171).
// Cross-wave coupling wasn't a cost; keep the wave-decoupled base (simpler,
// equal speed). Stall signature unchanged since R0: VALU 23%, HBM 25%,
// waves stalled ~90% of life. Last structural exposure: B-prologue loads
// issue AFTER Phase A's ~1700-FMA chain (empty vmem queue during the MLP)
// and COMP(0) eats their full latency at the A->B seam.
// R14: hoist the prologue INTO Phase A (plain code motion — R9/R10 showed
// LDS/barrier versions serialize). To fit registers, w2 stage splits into
// two halves (e0..19, e20..35; same FMA count; float4-clean writes at
// t9 0-4 / 5-8): peak = ring64 + td16 + ke16 + addr ~ 110.
// Schedule: [w1+BN] |f| LROWS(0..2) |f| w2h1+write; LROWS(3) |f| w2h2+write
// |f| COMP(0).. — mask-0 fences only (never rematerialized/regressed).
// x-loads stay first in queue (prologue fenced below w1 GEMM); slots 0-2
// covered by half1+half2 (~1200cy), slot 3 by half2+COMP(0).
// GATES: VGPR 95-125 (>128 = tier loss -> expect regression), WRITE ==
// 73728, conflicts 0, LDS 18432. Predict profiled 71 -> 62-67, harness
// 161-167. If flat with gates ok: seam latency insignificant -> R15 =
// ring-5 / prefetch distance 3 for the COMP steady state.

#define B_   8
#define H_   192
#define W_   192
#define CR_  16
#define TH_  8
#define TW_  16
#define TILES_X (W_/TW_)                    // 12
#define TILES_PER_IMG (TILES_X*(H_/TH_))    // 288
#define NBLK (B_*TILES_PER_IMG)             // 2304

constexpr float BN_EPS = 1e-3f;

__device__ __forceinline__ float4 mask4(float4 k, bool v) {
    k.x = v ? k.x : 0.f;
    k.y = v ? k.y : 0.f;
    k.z = v ? k.z : 0.f;
    k.w = v ? k.w : 0.f;
    return k;
}

__device__ __forceinline__ void fma4(float4& a, const float4 k, const float4 x) {
    a.x = fmaf(k.x, x.x, a.x);
    a.y = fmaf(k.y, x.y, a.y);
    a.z = fmaf(k.z, x.z, a.z);
    a.w = fmaf(k.w, x.w, a.w);
}

// Load row R (clamped) into ring slot S: 4 tap-columns {wA-1..wA+2}.
#define LROWS(S, R)                                                         \
    do {                                                                    \
        int rr_ = (R);                                                      \
        if (!INTERIOR) {                                                    \
            if ((unsigned)rr_ < (unsigned)H_) rv |= (1 << (S));             \
            else                              rv &= ~(1 << (S));            \
            rr_ = rr_ < 0 ? 0 : (rr_ >= H_ ? H_ - 1 : rr_);                 \
        }                                                                   \
        const int rb_ = rr_ * (W_ * 16);                                    \
        rg[S][0] = x4[rb_ + co[0]];                                         \
        rg[S][1] = x4[rb_ + co[1]];                                         \
        rg[S][2] = x4[rb_ + co[2]];                                         \
        rg[S][3] = x4[rb_ + co[3]];                                         \
    } while (0)

// Compute pixel row th0+I, output cols wA (taps 0..2) and wA+1 (taps 1..3).
// kq from THIS WAVE's private s_kern half: wave-local pixel p = I*8 + 2j.
#define COMP(I)                                                             \
    do {                                                                    \
        const float4* kqA_ = &s_half[((I) * 8 + 2 * j) * 9];                \
        const float4* kqB_ = kqA_ + 9;                                      \
        float4 aA_ = make_float4(0.f, 0.f, 0.f, 0.f);                       \
        float4 aB_ = make_float4(0.f, 0.f, 0.f, 0.f);                       \
        _Pragma("unroll")                                                   \
        for (int ti_ = 0; ti_ < 3; ++ti_) {                                 \
            const int s_ = ((I) + ti_) & 3;                                 \
            _Pragma("unroll")                                               \
            for (int tj_ = 0; tj_ < 3; ++tj_) {                             \
                float4 kA_ = kqA_[ti_ * 3 + tj_];                           \
                float4 kB_ = kqB_[ti_ * 3 + tj_];                           \
                if (!INTERIOR) {                                            \
                    kA_ = mask4(kA_, (((rv >> s_) & (cm >> tj_)) & 1));     \
                    kB_ = mask4(kB_, (((rv >> s_) & (cm >> (tj_ + 1))) & 1));\
                }                                                           \
                fma4(aA_, kA_, rg[s_][tj_]);                                \
                fma4(aB_, kB_, rg[s_][tj_ + 1]);                            \
            }                                                               \
        }                                                                   \
        const int ob_ = (th0 + (I)) * (W_ * 16);                            \
        o4[ob_ + (wA << 4) + c4i] = aA_;                                    \
        o4[ob_ + (wA << 4) + 16 + c4i] = aB_;                               \
    } while (0)

#define SFENCE __builtin_amdgcn_sched_barrier(0)

// Entire per-wave body: Phase A (kern gen) with mid-A B-prologue, then
// Phase B (9-tap multiply-reduce). No barriers; waves fully independent.
template <bool INTERIOR>
__device__ __forceinline__ void wave_body(
    const float* __restrict__ x,
    const float4* __restrict__ x4,
    float4* __restrict__ o4,
    float4* __restrict__ s_half,
    const float* __restrict__ w1, const float* __restrict__ b1,
    const float* __restrict__ gamma, const float* __restrict__ beta,
    const float* __restrict__ mean, const float* __restrict__ var,
    const float* __restrict__ w2, const float* __restrict__ b2,
    int img, int th0, int tw0w, int ln)
{
    // ---- Phase B addressing (early: the hoisted prologue needs it) ------
    const int j   = ln >> 4;      // col pair 0..3 -> cols 2j, 2j+1
    const int c4i = ln & 15;      // float4 channel chunk
    const int wA  = tw0w + 2 * j;

    int co[4];
    int cm = 0xF;
    #pragma unroll
    for (int tj = 0; tj < 4; ++tj) {
        int wc = wA - 1 + tj;
        if (!INTERIOR) {
            if ((unsigned)wc >= (unsigned)W_) cm &= ~(1 << tj);
            wc = wc < 0 ? 0 : (wc >= W_ ? W_ - 1 : wc);
        }
        co[tj] = (wc << 4) + c4i;
    }

    float4 rg[4][4];   // ring, all indices static
    int rv = 0xF;

    // ---- Phase A stage 1: w1 GEMM + BN ---------------------------------
    // x-loads enter the vmem queue FIRST (prologue is fenced below), and
    // pipeline per-c4 with the FMA chain (R10/R11: LDS staging serializes).
    float td[CR_];
    {
        const int r = ln >> 3, c8 = ln & 7;
        const int h = th0 + r, w = tw0w + c8;
        const float4* xp = reinterpret_cast<const float4*>(
            x + (((size_t)((img * H_ + h) * W_ + w)) << 6));

        #pragma unroll
        for (int d = 0; d < CR_; ++d) td[d] = 0.f;

        #pragma unroll
        for (int c4 = 0; c4 < 16; ++c4) {
            const float4 xv = xp[c4];
            const float xs[4] = {xv.x, xv.y, xv.z, xv.w};
            #pragma unroll
            for (int k = 0; k < 4; ++k) {
                const float* wr = w1 + (c4 * 4 + k) * CR_;
                #pragma unroll
                for (int d = 0; d < CR_; ++d)
                    td[d] = fmaf(xs[k], wr[d], td[d]);
            }
        }

        // + b1, BN (inference), ReLU — folded affine
        #pragma unroll
        for (int d = 0; d < CR_; ++d) {
            const float a = gamma[d] * rsqrtf(var[d] + BN_EPS);
            const float c = (b1[d] - mean[d]) * a + beta[d];
            td[d] = fmaxf(fmaf(td[d], a, c), 0.f);
        }
    }

    SFENCE;
    // ---- B-prologue, hoisted mid-A: slots 0..2 (rows th0-1..th0+1) ------
    // Latency covered by w2 halves (~1200cy of FMA) instead of exposed at
    // the A->B seam. Fences pin the loads in this region (no sink/remat).
    LROWS(0, th0 - 1);
    LROWS(1, th0 + 0);
    LROWS(2, th0 + 1);
    SFENCE;

    // ---- Phase A stage 2a: w2 outputs e0..19 + s_kern write -------------
    {
        float ke0[20];
        #pragma unroll
        for (int e = 0; e < 20; ++e) ke0[e] = b2[e];
        #pragma unroll
        for (int d = 0; d < CR_; ++d) {
            const float t = td[d];
            const float* wr = w2 + d * 36;
            #pragma unroll
            for (int e = 0; e < 20; ++e)
                ke0[e] = fmaf(t, wr[e], ke0[e]);
        }
        float4* skq = &s_half[ln * 9];
        #pragma unroll
        for (int t9 = 0; t9 < 5; ++t9)
            skq[t9] = make_float4(ke0[t9 * 4 + 0], ke0[t9 * 4 + 1],
                                  ke0[t9 * 4 + 2], ke0[t9 * 4 + 3]);
    }
    // Slot 3 (row th0+2): may hoist into half1 above (earlier issue is
    // fine); the fence below stops it sinking past half2. First use is
    // COMP(1) — covered by half2 + COMP(0).
    LROWS(3, th0 + 2);
    SFENCE;

    // ---- Phase A stage 2b: w2 outputs e20..35 + s_kern write ------------
    {
        float ke1[16];
        #pragma unroll
        for (int e = 0; e < 16; ++e) ke1[e] = b2[20 + e];
        #pragma unroll
        for (int d = 0; d < CR_; ++d) {
            const float t = td[d];
            const float* wr = w2 + d * 36 + 20;
            #pragma unroll
            for (int e = 0; e < 16; ++e)
                ke1[e] = fmaf(t, wr[e], ke1[e]);
        }
        float4* skq = &s_half[ln * 9];
        #pragma unroll
        for (int i = 0; i < 4; ++i)
            skq[5 + i] = make_float4(ke1[i * 4 + 0], ke1[i * 4 + 1],
                                     ke1[i * 4 + 2], ke1[i * 4 + 3]);
    }
    SFENCE;

    // ---- Phase B steady state (R12/R13-proven) --------------------------
    // COMP(0)'s kq ds_reads wait only on this wave's own ds_writes (in
    // flight just above); ring slots were issued 600-1800cy earlier.
    COMP(0); LROWS(0, th0 + 3);
    SFENCE;
    COMP(1); LROWS(1, th0 + 4);
    SFENCE;
    COMP(2); LROWS(2, th0 + 5);
    SFENCE;
    COMP(3); LROWS(3, th0 + 6);
    SFENCE;
    COMP(4); LROWS(0, th0 + 7);
    SFENCE;
    COMP(5); LROWS(1, th0 + 8);
    SFENCE;
    COMP(6);
    COMP(7);
}

#undef LROWS
#undef COMP

__global__ __launch_bounds__(128, 2)
void invol_fused(const float* __restrict__ x,
                 const float* __restrict__ w1,
                 const float* __restrict__ b1,
                 const float* __restrict__ gamma,
                 const float* __restrict__ beta,
                 const float* __restrict__ mean,
                 const float* __restrict__ var,
                 const float* __restrict__ w2,
                 const float* __restrict__ b2,
                 float* __restrict__ out)
{
    // Two wave-private halves: 64 px * 9 float4 each = 18 KB total.
    // Wave w only ever touches s_kern[w] — no cross-wave hazard, ever.
    __shared__ float4 s_kern[2][64 * 9];

    const int bid = blockIdx.x;
    // XCD swizzle: 2304 = 8 * 288; each XCD owns one image for L2 locality.
    const int img = bid & 7;
    const int tin = bid >> 3;
    const int th0 = (tin / TILES_X) * TH_;
    const int tw0 = (tin % TILES_X) * TW_;
    const int tid = threadIdx.x;
    const int wv  = tid >> 6;            // wave 0/1
    const int ln  = tid & 63;            // lane

    const float4* x4 = reinterpret_cast<const float4*>(x) +
                       (size_t)img * (H_ * W_ * 16);
    float4* o4 = reinterpret_cast<float4*>(out) +
                 (size_t)img * (H_ * W_ * 16);

    const bool interior = (th0 > 0) && (th0 + TH_ < H_) &&
                          (tw0 > 0) && (tw0 + TW_ < W_);
    if (interior)
        wave_body<true >(x, x4, o4, s_kern[wv], w1, b1, gamma, beta,
                         mean, var, w2, b2, img, th0, tw0 + 8 * wv, ln);
    else
        wave_body<false>(x, x4, o4, s_kern[wv], w1, b1, gamma, beta,
                         mean, var, w2, b2, img, th0, tw0 + 8 * wv, ln);
}

extern "C" void kernel_launch(void* const* d_in, const int* in_sizes, int n_in,
                              void* d_out, int out_size, void* d_ws, size_t ws_size,
                              hipStream_t stream) {
    const float* x     = (const float*)d_in[0];
    const float* w1    = (const float*)d_in[1];
    const float* b1    = (const float*)d_in[2];
    const float* gamma = (const float*)d_in[3];
    const float* beta  = (const float*)d_in[4];
    const float* mean  = (const float*)d_in[5];
    const float* var   = (const float*)d_in[6];
    const float* w2    = (const float*)d_in[7];
    const float* b2    = (const float*)d_in[8];
    float* out = (float*)d_out;

    invol_fused<<<dim3(NBLK), dim3(128), 0, stream>>>(
        x, w1, b1, gamma, beta, mean, var, w2, b2, out);
}

// Round 12
// 175.022 us; speedup vs baseline: 1.0240x; 1.0240x over previous
//
#include <hip/hip_runtime.h>

// Involution (B=8, H=W=192, C=64, G=4, K=3, R=4) — round 15.
// R14 post-mortem: mid-A prologue hoist REGRESSED (77us, WRITE 74000 =
// +272KB scratch, occ 17%) — ring live-range across w2 overwhelmed
// regalloc. Third failed A->B seam restructure (R9 split, R10/R11 LDS,
// R14 hoist). R12 is robustly best: 69.5 profiled / 168.9 harness.
// State: traffic near-minimal (FETCH 65MB < x 75.5MB, WRITE = output),
// grid 2304 ~ resident capacity -> duration = block lifetime, latency-
// stalled (~3us issue in ~30us life) at ~2 of 6.3 TB/s.
// R15 = R12 + ONE change: 5-slot ring, prefetch distance 3 (pre-registered
// at R13). slot(r) = (r+1)%5; prologue rows -1..+3 (20 loads in flight);
// region I: COMP(I); LROWS(I%5, I+4) — first use COMP(I+3), 3 regions
// after issue (~450cy coverage vs L2/L3 ~200-600cy). +16 VGPR, nothing
// else touched.
// GATES: VGPR 90-110 (>125 fail), WRITE == 73728 exactly, conflicts 0,
// LDS 18432. Predict profiled 69.5 -> 61-67, harness -> 161-167.
// If flat: per-wave MLP exhausted -> 4-lane/pixel Phase-A GEMV split
// (L2-request amplification, last untried structure) or declare.

#define B_   8
#define H_   192
#define W_   192
#define CR_  16
#define TH_  8
#define TW_  16
#define TILES_X (W_/TW_)                    // 12
#define TILES_PER_IMG (TILES_X*(H_/TH_))    // 288
#define NBLK (B_*TILES_PER_IMG)             // 2304
#define NPIX (TH_*TW_)                      // 128

constexpr float BN_EPS = 1e-3f;

__device__ __forceinline__ float4 mask4(float4 k, bool v) {
    k.x = v ? k.x : 0.f;
    k.y = v ? k.y : 0.f;
    k.z = v ? k.z : 0.f;
    k.w = v ? k.w : 0.f;
    return k;
}

__device__ __forceinline__ void fma4(float4& a, const float4 k, const float4 x) {
    a.x = fmaf(k.x, x.x, a.x);
    a.y = fmaf(k.y, x.y, a.y);
    a.z = fmaf(k.z, x.z, a.z);
    a.w = fmaf(k.w, x.w, a.w);
}

// Load row R (clamped) into ring slot S: 4 tap-columns {wA-1..wA+2}.
#define LROWS(S, R)                                                         \
    do {                                                                    \
        int rr_ = (R);                                                      \
        if (!INTERIOR) {                                                    \
            if ((unsigned)rr_ < (unsigned)H_) rv |= (1 << (S));             \
            else                              rv &= ~(1 << (S));            \
            rr_ = rr_ < 0 ? 0 : (rr_ >= H_ ? H_ - 1 : rr_);                 \
        }                                                                   \
        const int rb_ = rr_ * (W_ * 16);                                    \
        rg[S][0] = x4[rb_ + co[0]];                                         \
        rg[S][1] = x4[rb_ + co[1]];                                         \
        rg[S][2] = x4[rb_ + co[2]];                                         \
        rg[S][3] = x4[rb_ + co[3]];                                         \
    } while (0)

// Compute pixel row th0+I, output cols wA (taps 0..2) and wA+1 (taps 1..3).
// Ring slot for row r is (r+1)%5 -> COMP(I) reads slots (I+ti)%5.
#define COMP(I)                                                             \
    do {                                                                    \
        const float4* kqA_ = &s_kern[((I) * TW_ + 2 * wslot) * 9];          \
        const float4* kqB_ = kqA_ + 9;                                      \
        float4 aA_ = make_float4(0.f, 0.f, 0.f, 0.f);                       \
        float4 aB_ = make_float4(0.f, 0.f, 0.f, 0.f);                       \
        _Pragma("unroll")                                                   \
        for (int ti_ = 0; ti_ < 3; ++ti_) {                                 \
            const int s_ = ((I) + ti_) % 5;                                 \
            _Pragma("unroll")                                               \
            for (int tj_ = 0; tj_ < 3; ++tj_) {                             \
                float4 kA_ = kqA_[ti_ * 3 + tj_];                           \
                float4 kB_ = kqB_[ti_ * 3 + tj_];                           \
                if (!INTERIOR) {                                            \
                    kA_ = mask4(kA_, (((rv >> s_) & (cm >> tj_)) & 1));     \
                    kB_ = mask4(kB_, (((rv >> s_) & (cm >> (tj_ + 1))) & 1));\
                }                                                           \
                fma4(aA_, kA_, rg[s_][tj_]);                                \
                fma4(aB_, kB_, rg[s_][tj_ + 1]);                            \
            }                                                               \
        }                                                                   \
        const int ob_ = (th0 + (I)) * (W_ * 16);                            \
        o4[ob_ + (wA << 4) + c4i] = aA_;                                    \
        o4[ob_ + (wA << 4) + 16 + c4i] = aB_;                               \
    } while (0)

#define SFENCE __builtin_amdgcn_sched_barrier(0)

template <bool INTERIOR>
__device__ __forceinline__ void phase_b(const float4* __restrict__ x4,
                                        float4* __restrict__ o4,
                                        const float4* __restrict__ s_kern,
                                        int th0, int tw0, int tid)
{
    const int wslot = tid >> 4;   // 0..7 -> output cols 2w, 2w+1
    const int c4i   = tid & 15;   // float4 channel chunk
    const int wA = tw0 + 2 * wslot;

    // 4 tap-column float4-offsets {wA-1 .. wA+2} (clamped; validity
    // zeroes the kern weight, matching zero-padding semantics).
    int co[4];
    int cm = 0xF;
    #pragma unroll
    for (int tj = 0; tj < 4; ++tj) {
        int wc = wA - 1 + tj;
        if (!INTERIOR) {
            if ((unsigned)wc >= (unsigned)W_) cm &= ~(1 << tj);
            wc = wc < 0 ? 0 : (wc >= W_ ? W_ - 1 : wc);
        }
        co[tj] = (wc << 4) + c4i;
    }

    float4 rg[5][4];   // 80-reg ring, all indices static
    int rv = 0x1F;

    // Prologue loads BEFORE the barrier: rows th0-1 .. th0+3 (20 loads
    // in flight) stream while the other wave finishes Phase A.
    LROWS(0, th0 - 1);
    LROWS(1, th0 + 0);
    LROWS(2, th0 + 1);
    LROWS(3, th0 + 2);
    LROWS(4, th0 + 3);

    __syncthreads();   // s_kern (both waves) now visible

    SFENCE;
    // Steady state: region I = { COMP(I), prefetch row th0+I+4 }.
    // Prefetch lands in the slot retired by COMP(I) (held row I-1);
    // first use is COMP(I+3) — THREE regions of FMA+LDS work after issue.
    COMP(0); LROWS(0, th0 + 4);
    SFENCE;
    COMP(1); LROWS(1, th0 + 5);
    SFENCE;
    COMP(2); LROWS(2, th0 + 6);
    SFENCE;
    COMP(3); LROWS(3, th0 + 7);
    SFENCE;
    COMP(4); LROWS(4, th0 + 8);
    SFENCE;
    COMP(5);
    SFENCE;
    COMP(6);
    COMP(7);
}

#undef LROWS
#undef COMP

__global__ __launch_bounds__(128, 2)
void invol_fused(const float* __restrict__ x,
                 const float* __restrict__ w1,
                 const float* __restrict__ b1,
                 const float* __restrict__ gamma,
                 const float* __restrict__ beta,
                 const float* __restrict__ mean,
                 const float* __restrict__ var,
                 const float* __restrict__ w2,
                 const float* __restrict__ b2,
                 float* __restrict__ out)
{
    // 128 pixels * 9 float4 (36 kern floats, tap-major, g minor) = 18 KB
    __shared__ float4 s_kern[NPIX * 9];

    const int bid = blockIdx.x;
    // XCD swizzle: 2304 = 8 * 288; each XCD owns one image for L2 locality.
    const int img = bid & 7;
    const int tin = bid >> 3;
    const int th0 = (tin / TILES_X) * TH_;
    const int tw0 = (tin % TILES_X) * TW_;
    const int tid = threadIdx.x;

    // ---------------- Phase A: kernel generation (1 thread = 1 pixel) -------
    // Strided-direct global reads, DELIBERATELY: each c4 iteration's FMAs
    // wait only on load c4 -> progressive load/FMA overlap. LDS staging
    // (R10 block-scope, R11 wave-scope) and mid-A hoist (R14) all lost.
    {
        const int r = tid >> 4, cc = tid & 15;
        const int h = th0 + r, w = tw0 + cc;
        const float4* xp = reinterpret_cast<const float4*>(
            x + (((size_t)((img * H_ + h) * W_ + w)) << 6));

        float td[CR_];
        #pragma unroll
        for (int d = 0; d < CR_; ++d) td[d] = 0.f;

        // t = x @ w1   (weight addresses wave-uniform -> s_load, SMEM pipe)
        #pragma unroll
        for (int c4 = 0; c4 < 16; ++c4) {
            const float4 xv = xp[c4];
            const float xs[4] = {xv.x, xv.y, xv.z, xv.w};
            #pragma unroll
            for (int k = 0; k < 4; ++k) {
                const float* wr = w1 + (c4 * 4 + k) * CR_;
                #pragma unroll
                for (int d = 0; d < CR_; ++d)
                    td[d] = fmaf(xs[k], wr[d], td[d]);
            }
        }

        // + b1, BN (inference), ReLU — folded affine
        #pragma unroll
        for (int d = 0; d < CR_; ++d) {
            const float a = gamma[d] * rsqrtf(var[d] + BN_EPS);
            const float c = (b1[d] - mean[d]) * a + beta[d];
            td[d] = fmaxf(fmaf(td[d], a, c), 0.f);
        }

        // kern = t @ w2 + b2  (e = tap*4 + g)
        float ke[36];
        #pragma unroll
        for (int e = 0; e < 36; ++e) ke[e] = b2[e];
        #pragma unroll
        for (int d = 0; d < CR_; ++d) {
            const float t = td[d];
            const float* wr = w2 + d * 36;
            #pragma unroll
            for (int e = 0; e < 36; ++e)
                ke[e] = fmaf(t, wr[e], ke[e]);
        }

        // stride 36 words (144 B): conflict-free b128 (measured 0 conflicts)
        float4* skq = &s_kern[tid * 9];
        #pragma unroll
        for (int t9 = 0; t9 < 9; ++t9)
            skq[t9] = make_float4(ke[t9 * 4 + 0], ke[t9 * 4 + 1],
                                  ke[t9 * 4 + 2], ke[t9 * 4 + 3]);
    }

    // ---------------- Phase B: 9-tap multiply-reduce, adjacent col pairs ----
    // (barrier is inside phase_b, after the B-prologue loads issue; the
    // interior/boundary branch is block-uniform so the barrier is legal)
    const float4* x4 = reinterpret_cast<const float4*>(x) +
                       (size_t)img * (H_ * W_ * 16);
    float4* o4 = reinterpret_cast<float4*>(out) +
                 (size_t)img * (H_ * W_ * 16);

    const bool interior = (th0 > 0) && (th0 + TH_ < H_) &&
                          (tw0 > 0) && (tw0 + TW_ < W_);
    if (interior)
        phase_b<true >(x4, o4, s_kern, th0, tw0, tid);
    else
        phase_b<false>(x4, o4, s_kern, th0, tw0, tid);
}

extern "C" void kernel_launch(void* const* d_in, const int* in_sizes, int n_in,
                              void* d_out, int out_size, void* d_ws, size_t ws_size,
                              hipStream_t stream) {
    const float* x     = (const float*)d_in[0];
    const float* w1    = (const float*)d_in[1];
    const float* b1    = (const float*)d_in[2];
    const float* gamma = (const float*)d_in[3];
    const float* beta  = (const float*)d_in[4];
    const float* mean  = (const float*)d_in[5];
    const float* var   = (const float*)d_in[6];
    const float* w2    = (const float*)d_in[7];
    const float* b2    = (const float*)d_in[8];
    float* out = (float*)d_out;

    invol_fused<<<dim3(NBLK), dim3(128), 0, stream>>>(
        x, w1, b1, gamma, beta, mean, var, w2, b2, out);
}